// Round 7
// baseline (247.095 us; speedup 1.0000x reference)
//
#include <hip/hip_runtime.h>
#include <stdint.h>
#include <math.h>

// Attention: out = dropout(softmax(8 * Q K^T)) V, B=4 H=16 S=1024 D=64 fp32.
// R7 structure (DS-pipe bound fix): compute S^T = K Q^T so that
//  - C-layout col = q  -> softmax row state is PER-LANE (1 q per lane per u):
//    row max/sum = 15 in-lane ops + 2 shuffles (was 4-step shuffle x 8 rows).
//  - P lands with 4 consecutive keys per lane -> ds_write_b64 x8 (was 32 u16).
//  - PV computed as O^T (A = Vt from LDS, B = P from LDS): o_acc col = q, so
//    alpha rescale + epilogue scale are per-lane scalars; float4 stores.
// Staging: prep_kv pre-splits K into (Kh,Kl) bf16 + V^T bf16, XOR-chunk
// swizzled tiles in d_ws; attn kernel DMAs via global_load_lds (R5's proven
// two-barrier single-buffer loop; R6's dyn-indexed dbuf regressed because the
// compiler inserts vmcnt(0) before ds_read on possible LDS-DMA aliasing).
// Dropout: deferred correction (candidate list + dense threefry at the end).
// Threefry: counter-mode, bits = y0^y1 (VERIFIED R2); lazy threshold -11
// (skipped entries contribute <= ~1e-4 masked or not).

constexpr int Bn = 4, Hn = 16, Sn = 1024, Dn = 64;
constexpr int NT = 256;
constexpr int TQ = 128, TK = 64;
constexpr int CAP = 256;  // per-wave candidate list capacity (overflow path exact)

typedef short s16x8 __attribute__((ext_vector_type(8)));
typedef short s16x4 __attribute__((ext_vector_type(4)));
typedef float f32x4 __attribute__((ext_vector_type(4)));

__device__ __forceinline__ uint16_t f2bf(float x) {  // RNE float->bf16
  uint32_t u = __float_as_uint(x);
  return (uint16_t)((u + 0x7fffu + ((u >> 16) & 1u)) >> 16);
}
__device__ __forceinline__ float bf2f(uint16_t h) {
  return __uint_as_float(((uint32_t)h) << 16);
}

__device__ __forceinline__ void tf_round(uint32_t& x0, uint32_t& x1, const int r) {
  x0 += x1;
  x1 = (x1 << r) | (x1 >> (32 - r));
  x1 ^= x0;
}

// threefry2x32, key(42)=(0,42), counter (0, j), bits = y0^y1  [VERIFIED R2]
__device__ __noinline__ int keep_bit(uint32_t j) {
  uint32_t x0 = 0u, x1 = j;
  const uint32_t k0 = 0u, k1v = 42u;
  const uint32_t k2v = k0 ^ k1v ^ 0x1BD11BDAu;
  x0 += k0; x1 += k1v;
  tf_round(x0, x1, 13); tf_round(x0, x1, 15); tf_round(x0, x1, 26); tf_round(x0, x1, 6);
  x0 += k1v; x1 += k2v + 1u;
  tf_round(x0, x1, 17); tf_round(x0, x1, 29); tf_round(x0, x1, 16); tf_round(x0, x1, 24);
  x0 += k2v; x1 += k0 + 2u;
  tf_round(x0, x1, 13); tf_round(x0, x1, 15); tf_round(x0, x1, 26); tf_round(x0, x1, 6);
  x0 += k0; x1 += k1v + 3u;
  tf_round(x0, x1, 17); tf_round(x0, x1, 29); tf_round(x0, x1, 16); tf_round(x0, x1, 24);
  x0 += k1v; x1 += k2v + 4u;
  tf_round(x0, x1, 13); tf_round(x0, x1, 15); tf_round(x0, x1, 26); tf_round(x0, x1, 6);
  x0 += k2v; x1 += k0 + 5u;
  uint32_t bits = x0 ^ x1;
  float u = __uint_as_float((bits >> 9) | 0x3f800000u) - 1.0f;
  return u < 0.9f;
}

// ---------------- pre-pass: K split + V transpose, swizzled bf16 tiles ----------------
__global__ __launch_bounds__(NT) void prep_kv(const float* __restrict__ K,
                                              const float* __restrict__ V,
                                              uint16_t* __restrict__ Khg,
                                              uint16_t* __restrict__ Klg,
                                              uint16_t* __restrict__ Vtg) {
  __shared__ float Vl[TK][Dn + 1];
  const int t = threadIdx.x;
  const int kt = blockIdx.x;   // 0..15
  const int bh = blockIdx.y;   // 0..63
  const int r = t >> 2, qd = t & 3;
  const size_t tile = ((size_t)bh * 16 + kt) * 4096;
  const float* ksrc = K + ((size_t)bh * Sn + (size_t)(kt * TK + r)) * Dn + qd * 16;
  const float* vsrc = V + ((size_t)bh * Sn + (size_t)(kt * TK + r)) * Dn + qd * 16;

#pragma unroll
  for (int half = 0; half < 2; ++half) {
    float4 a = *(const float4*)(ksrc + half * 8);
    float4 b = *(const float4*)(ksrc + half * 8 + 4);
    float xs[8] = {a.x, a.y, a.z, a.w, b.x, b.y, b.z, b.w};
    s16x8 hv, lv;
#pragma unroll
    for (int j = 0; j < 8; ++j) {
      uint16_t hb = f2bf(xs[j]);
      hv[j] = (short)hb;
      lv[j] = (short)f2bf(xs[j] - bf2f(hb));
    }
    const int sc = (qd * 2 + half) ^ (r & 7);
    *(s16x8*)&Khg[tile + (size_t)r * 64 + sc * 8] = hv;
    *(s16x8*)&Klg[tile + (size_t)r * 64 + sc * 8] = lv;
    float4 va = *(const float4*)(vsrc + half * 8);
    float4 vb = *(const float4*)(vsrc + half * 8 + 4);
    *(float4*)&Vl[r][qd * 16 + half * 8] = va;
    *(float4*)&Vl[r][qd * 16 + half * 8 + 4] = vb;
  }
  __syncthreads();
#pragma unroll
  for (int half = 0; half < 2; ++half) {
    s16x8 ov;
#pragma unroll
    for (int j = 0; j < 8; ++j) ov[j] = (short)f2bf(Vl[qd * 16 + half * 8 + j][r]);
    const int sc = (qd * 2 + half) ^ (r & 7);
    *(s16x8*)&Vtg[tile + (size_t)r * 64 + sc * 8] = ov;
  }
}

// ---------------- main flash kernel: S^T orientation, TQ=128 ----------------
__global__ __launch_bounds__(NT) void attn_mfma5(
    const float* __restrict__ Q, const uint16_t* __restrict__ Khg,
    const uint16_t* __restrict__ Klg, const uint16_t* __restrict__ Vtg,
    const float* __restrict__ V, const int* __restrict__ scale_ptr,
    float* __restrict__ out) {
  __shared__ uint16_t KhS[TK * Dn];      // 8 KB, unpadded (DMA dest), swizzled rows
  __shared__ uint16_t KlS[TK * Dn];
  __shared__ uint16_t VtS[TK * Dn];
  __shared__ uint16_t PS[4 * 32 * 64];   // per-wave P[q][key], XOR-chunk swizzled
  __shared__ uint32_t Lm[4][CAP];        // per-wave candidate list: (rw<<10)|key
  __shared__ float Lsv[4][CAP];          // candidate logit s
  __shared__ float mfin[4][32];          // per-wave final row max

  const int t = threadIdx.x;
  const int w = t >> 6;
  const int lane = t & 63;
  const int l16 = lane & 15;
  const int quad = lane >> 4;
  const int xl = l16 & 7;                // XOR swizzle key

  const int b = blockIdx.z, h = blockIdx.y;
  const int qbase = blockIdx.x * TQ;
  const int bh = b * Hn + h;
  const float qscale = (float)(*scale_ptr);

  // per-wave DMA segment offsets (elements): wave w covers segs {2w, 2w+1}
  const int e0off = (w * 2) * 512 + lane * 8;
  const int e1off = (w * 2 + 1) * 512 + lane * 8;
  const size_t tbase = (size_t)bh * 16 * 4096;
  const int psw = w * 2048;              // per-wave PS base (elements)

  // ---- Q B-frags (pre-scaled by scale_factor): wave w owns q rows
  // qbase + w*32 + u*16 + l16;  frag layout B[n=l16][k=quad*8+j] ----
  s16x8 qh[2][2], ql[2][2];
#pragma unroll
  for (int u = 0; u < 2; ++u) {
    const int qrow = qbase + w * 32 + u * 16 + l16;
    const float* src = Q + ((size_t)bh * Sn + (size_t)qrow) * Dn;
#pragma unroll
    for (int ks = 0; ks < 2; ++ks) {
      float4 x0 = *(const float4*)(src + ks * 32 + quad * 8);
      float4 x1 = *(const float4*)(src + ks * 32 + quad * 8 + 4);
      float xv[8] = {x0.x, x0.y, x0.z, x0.w, x1.x, x1.y, x1.z, x1.w};
#pragma unroll
      for (int j = 0; j < 8; ++j) {
        const float xs = xv[j] * qscale;
        uint16_t hb = f2bf(xs);
        qh[u][ks][j] = (short)hb;
        ql[u][ks][j] = (short)f2bf(xs - bf2f(hb));
      }
    }
  }

  // per-lane softmax state: ONE q per lane per u
  float m_r[2] = {-INFINITY, -INFINITY};
  float l_r[2] = {0.0f, 0.0f};
  // O^T accumulator: o_acc[u][c][r] = O[q = u*16+l16][dv = c*16+quad*4+r]
  f32x4 o_acc[2][4];
#pragma unroll
  for (int u = 0; u < 2; ++u)
#pragma unroll
    for (int c = 0; c < 4; ++c) o_acc[u][c] = (f32x4){0.f, 0.f, 0.f, 0.f};

  const uint32_t hbase = (uint32_t)bh * (uint32_t)Sn;
  int lbase = 0;  // per-wave list fill (wave-uniform)

  for (int kt = 0; kt < Sn / TK; ++kt) {
    const int kbase = kt * TK;
    __syncthreads();  // all waves done reading prev tile's LDS

    // ---- DMA staging (single buffer; R5 proven structure) ----
    {
      const size_t tile = tbase + (size_t)kt * 4096;
      __builtin_amdgcn_global_load_lds(
          (const __attribute__((address_space(1))) uint32_t*)(Khg + tile + e0off),
          (__attribute__((address_space(3))) uint32_t*)(KhS + e0off), 16, 0, 0);
      __builtin_amdgcn_global_load_lds(
          (const __attribute__((address_space(1))) uint32_t*)(Khg + tile + e1off),
          (__attribute__((address_space(3))) uint32_t*)(KhS + e1off), 16, 0, 0);
      __builtin_amdgcn_global_load_lds(
          (const __attribute__((address_space(1))) uint32_t*)(Klg + tile + e0off),
          (__attribute__((address_space(3))) uint32_t*)(KlS + e0off), 16, 0, 0);
      __builtin_amdgcn_global_load_lds(
          (const __attribute__((address_space(1))) uint32_t*)(Klg + tile + e1off),
          (__attribute__((address_space(3))) uint32_t*)(KlS + e1off), 16, 0, 0);
      __builtin_amdgcn_global_load_lds(
          (const __attribute__((address_space(1))) uint32_t*)(Vtg + tile + e0off),
          (__attribute__((address_space(3))) uint32_t*)(VtS + e0off), 16, 0, 0);
      __builtin_amdgcn_global_load_lds(
          (const __attribute__((address_space(1))) uint32_t*)(Vtg + tile + e1off),
          (__attribute__((address_space(3))) uint32_t*)(VtS + e1off), 16, 0, 0);
    }
    __syncthreads();  // vmcnt drained -> deposits visible

    // ---- S^T = K Q^T: A = K tile (LDS), B = Q (regs), split-bf16 3-MFMA.
    // C-layout: row = key-in-tile = quad*4+r, col = q = l16; c = key-block. ----
    f32x4 sacc[2][4];
#pragma unroll
    for (int u = 0; u < 2; ++u)
#pragma unroll
      for (int c = 0; c < 4; ++c) sacc[u][c] = (f32x4){0.f, 0.f, 0.f, 0.f};
#pragma unroll
    for (int ks = 0; ks < 2; ++ks) {
#pragma unroll
      for (int c = 0; c < 4; ++c) {
        const int boff = (c * 16 + l16) * 64 + (((ks * 4 + quad) ^ xl) * 8);
        const s16x8 khv = *(const s16x8*)&KhS[boff];
        const s16x8 klv = *(const s16x8*)&KlS[boff];
#pragma unroll
        for (int u = 0; u < 2; ++u) {
          sacc[u][c] = __builtin_amdgcn_mfma_f32_16x16x32_bf16(khv, qh[u][ks], sacc[u][c], 0, 0, 0);
          sacc[u][c] = __builtin_amdgcn_mfma_f32_16x16x32_bf16(khv, ql[u][ks], sacc[u][c], 0, 0, 0);
          sacc[u][c] = __builtin_amdgcn_mfma_f32_16x16x32_bf16(klv, qh[u][ks], sacc[u][c], 0, 0, 0);
        }
      }
    }

    // ---- online softmax (per-lane row state) + candidate push + P store ----
#pragma unroll
    for (int u = 0; u < 2; ++u) {
      float mx = sacc[u][0][0];
#pragma unroll
      for (int c = 0; c < 4; ++c)
#pragma unroll
        for (int r = 0; r < 4; ++r) mx = fmaxf(mx, sacc[u][c][r]);
      mx = fmaxf(mx, __shfl_xor(mx, 16));
      mx = fmaxf(mx, __shfl_xor(mx, 32));  // row max over all 64 keys of tile
      const float mn = fmaxf(m_r[u], mx);
      const float al = __expf(m_r[u] - mn);  // 0 on first tile
      m_r[u] = mn;
#pragma unroll
      for (int c = 0; c < 4; ++c)
#pragma unroll
        for (int r = 0; r < 4; ++r) o_acc[u][c][r] *= al;

      float pv[4][4], dvv[4][4];
      float rs = 0.0f;
#pragma unroll
      for (int c = 0; c < 4; ++c)
#pragma unroll
        for (int r = 0; r < 4; ++r) {
          dvv[c][r] = sacc[u][c][r] - mn;
          pv[c][r] = __expf(dvv[c][r]);
          rs += pv[c][r];  // UNMASKED row sum (softmax normalizes before dropout)
        }

      // candidate push: gate on tile-row-max vs running max (wave-uniform-ish)
      if (__ballot(mx - mn > -11.0f) != 0ull) {
#pragma unroll
        for (int c = 0; c < 4; ++c)
#pragma unroll
          for (int r = 0; r < 4; ++r) {
            const uint64_t mc = __ballot(dvv[c][r] > -11.0f);
            if (mc != 0ull) {
              if (lbase + 64 <= CAP) {
                const int slot = lbase + (int)__popcll(mc & ((1ull << lane) - 1ull));
                if (dvv[c][r] > -11.0f) {
                  const uint32_t rw = (uint32_t)(u * 16 + l16);
                  Lm[w][slot] = (rw << 10) | (uint32_t)(kbase + c * 16 + quad * 4 + r);
                  Lsv[w][slot] = dvv[c][r] + mn;
                }
                lbase += (int)__popcll(mc);
              } else if (dvv[c][r] > -11.0f) {  // overflow: inline exact dropout
                const uint32_t j =
                    (hbase + (uint32_t)(qbase + w * 32 + u * 16 + l16)) * (uint32_t)Sn +
                    (uint32_t)(kbase + c * 16 + quad * 4 + r);
                if (!keep_bit(j)) pv[c][r] = 0.0f;  // rs already added (unmasked)
              }
            }
          }
      }

      // P store: 4 consecutive keys per (c) -> b64, XOR-chunk swizzled
#pragma unroll
      for (int c = 0; c < 4; ++c) {
        s16x4 pk;
#pragma unroll
        for (int r = 0; r < 4; ++r) pk[r] = (short)f2bf(pv[c][r]);
        const int pos = (c * 2 + (quad >> 1)) ^ xl;
        *(s16x4*)&PS[psw + (u * 16 + l16) * 64 + pos * 8 + (quad & 1) * 4] = pk;
      }

      rs += __shfl_xor(rs, 16);
      rs += __shfl_xor(rs, 32);
      l_r[u] = l_r[u] * al + rs;
    }

    // ---- PV as O^T: A = Vt (LDS), B = P (LDS, same-wave RAW) ----
#pragma unroll
    for (int ks2 = 0; ks2 < 2; ++ks2) {
      s16x8 pb[2];
#pragma unroll
      for (int u = 0; u < 2; ++u)
        pb[u] = *(const s16x8*)&PS[psw + (u * 16 + l16) * 64 + (((ks2 * 4 + quad) ^ xl) * 8)];
#pragma unroll
      for (int c = 0; c < 4; ++c) {
        const int voff = (c * 16 + l16) * 64 + (((ks2 * 4 + quad) ^ xl) * 8);
        const s16x8 vb = *(const s16x8*)&VtS[voff];
#pragma unroll
        for (int u = 0; u < 2; ++u)
          o_acc[u][c] = __builtin_amdgcn_mfma_f32_16x16x32_bf16(vb, pb[u], o_acc[u][c], 0, 0, 0);
      }
    }
  }

  // ---- drain: dense threefry over candidate list, subtract dropped p*V ----
  if (quad == 0) {
#pragma unroll
    for (int u = 0; u < 2; ++u) mfin[w][u * 16 + l16] = m_r[u];
  }
  for (int e0 = 0; e0 < lbase; e0 += 64) {
    const int e = e0 + lane;
    const bool valid = e < lbase;
    const uint32_t meta = valid ? Lm[w][e] : 0u;
    const float sv = valid ? Lsv[w][e] : 0.0f;
    const uint32_t rwv = meta >> 10, keyv = meta & 1023u;
    const uint32_t grow = (uint32_t)(qbase + w * 32) + rwv;
    const uint32_t j = (hbase + grow) * (uint32_t)Sn + keyv;
    const int kb = keep_bit(j);  // dense: all 64 lanes productive
    uint64_t dm = __ballot(valid && !kb);
    while (dm != 0ull) {
      const int src = (int)__builtin_ctzll(dm);
      dm &= dm - 1ull;
      const uint32_t meta_s = (uint32_t)__builtin_amdgcn_readlane((int)meta, src);
      const float sv_s =
          __uint_as_float((uint32_t)__builtin_amdgcn_readlane((int)__float_as_uint(sv), src));
      const int rw = (int)(meta_s >> 10);
      const int key = (int)(meta_s & 1023u);
      const float p = __expf(sv_s - mfin[w][rw]);
      const float pb2 = bf2f(f2bf(p));
      if ((rw & 15) == l16) {  // the 4 quads owning column q participate
        const float* vp = V + ((size_t)bh * Sn + (size_t)key) * Dn;
        if ((rw >> 4) == 0) {
#pragma unroll
          for (int c = 0; c < 4; ++c) {
            float4 vv = *(const float4*)(vp + c * 16 + quad * 4);
            o_acc[0][c][0] = fmaf(-pb2, bf2f(f2bf(vv.x)), o_acc[0][c][0]);
            o_acc[0][c][1] = fmaf(-pb2, bf2f(f2bf(vv.y)), o_acc[0][c][1]);
            o_acc[0][c][2] = fmaf(-pb2, bf2f(f2bf(vv.z)), o_acc[0][c][2]);
            o_acc[0][c][3] = fmaf(-pb2, bf2f(f2bf(vv.w)), o_acc[0][c][3]);
          }
        } else {
#pragma unroll
          for (int c = 0; c < 4; ++c) {
            float4 vv = *(const float4*)(vp + c * 16 + quad * 4);
            o_acc[1][c][0] = fmaf(-pb2, bf2f(f2bf(vv.x)), o_acc[1][c][0]);
            o_acc[1][c][1] = fmaf(-pb2, bf2f(f2bf(vv.y)), o_acc[1][c][1]);
            o_acc[1][c][2] = fmaf(-pb2, bf2f(f2bf(vv.z)), o_acc[1][c][2]);
            o_acc[1][c][3] = fmaf(-pb2, bf2f(f2bf(vv.w)), o_acc[1][c][3]);
          }
        }
      }
    }
  }

  // ---- epilogue: out[q][dv] = O^T / (l * 0.9); per-lane scalar scale ----
#pragma unroll
  for (int u = 0; u < 2; ++u) {
    const float inv = 1.0f / (l_r[u] * 0.9f);
    const size_t obase = ((size_t)bh * Sn + (size_t)(qbase + w * 32 + u * 16 + l16)) * Dn;
#pragma unroll
    for (int c = 0; c < 4; ++c) {
      float4 ov;
      ov.x = o_acc[u][c][0] * inv;
      ov.y = o_acc[u][c][1] * inv;
      ov.z = o_acc[u][c][2] * inv;
      ov.w = o_acc[u][c][3] * inv;
      *(float4*)(out + obase + c * 16 + quad * 4) = ov;
    }
  }
}

// ---------------- fallback (R3 kernel, verbatim): used only if ws too small ----------------
constexpr int KST = 72;
__global__ __launch_bounds__(NT) void attn_fallback(
    const float* __restrict__ Q, const float* __restrict__ K,
    const float* __restrict__ V, const int* __restrict__ scale_ptr,
    float* __restrict__ out) {
  __shared__ uint16_t KhS[64 * KST];
  __shared__ uint16_t KlS[64 * KST];
  __shared__ uint16_t VtS[Dn * KST];
  __shared__ uint16_t PSf[4 * 16 * KST];

  const int t = threadIdx.x;
  const int w = t >> 6;
  const int lane = t & 63;
  const int l16 = lane & 15;
  const int quad = lane >> 4;
  const int b = blockIdx.z, h = blockIdx.y;
  const int qbase = blockIdx.x * 64;
  const size_t bh = (size_t)b * Hn + h;
  const float scale = (float)(*scale_ptr);
  const float* Kp = K + bh * Sn * Dn;
  const float* Vp = V + bh * Sn * Dn;

  const int qrow = qbase + w * 16 + l16;
  const float* Qp = Q + (bh * Sn + (size_t)qrow) * Dn;
  s16x8 qh[2], ql[2];
#pragma unroll
  for (int ks = 0; ks < 2; ++ks) {
    const float* src = Qp + ks * 32 + quad * 8;
    float4 x0 = *(const float4*)(src);
    float4 x1 = *(const float4*)(src + 4);
    float xv[8] = {x0.x, x0.y, x0.z, x0.w, x1.x, x1.y, x1.z, x1.w};
#pragma unroll
    for (int j = 0; j < 8; ++j) {
      uint16_t hb = f2bf(xv[j]);
      qh[ks][j] = (short)hb;
      ql[ks][j] = (short)f2bf(xv[j] - bf2f(hb));
    }
  }
  const int kr = t >> 2;
  const int qd = t & 3;
  float m_r[4], l_r[4];
#pragma unroll
  for (int r = 0; r < 4; ++r) { m_r[r] = -INFINITY; l_r[r] = 0.0f; }
  f32x4 o_acc[4];
#pragma unroll
  for (int c = 0; c < 4; ++c) o_acc[c] = (f32x4){0.f, 0.f, 0.f, 0.f};
  const uint32_t rowlin = ((uint32_t)(b * Hn + h)) * (uint32_t)Sn +
                          (uint32_t)(qbase + w * 16 + quad * 4);
  for (int kt = 0; kt < Sn / 64; ++kt) {
    const int kbase = kt * 64;
    __syncthreads();
    {
      const float* ksrc = Kp + (size_t)(kbase + kr) * Dn + qd * 16;
#pragma unroll
      for (int half = 0; half < 2; ++half) {
        float4 a = *(const float4*)(ksrc + half * 8);
        float4 b2 = *(const float4*)(ksrc + half * 8 + 4);
        float xs[8] = {a.x, a.y, a.z, a.w, b2.x, b2.y, b2.z, b2.w};
        s16x8 hv, lv;
#pragma unroll
        for (int j = 0; j < 8; ++j) {
          uint16_t hb = f2bf(xs[j]);
          hv[j] = (short)hb;
          lv[j] = (short)f2bf(xs[j] - bf2f(hb));
        }
        *(s16x8*)&KhS[kr * KST + qd * 16 + half * 8] = hv;
        *(s16x8*)&KlS[kr * KST + qd * 16 + half * 8] = lv;
      }
      const float* vsrc = Vp + (size_t)(kbase + kr) * Dn + qd * 16;
#pragma unroll
      for (int half = 0; half < 2; ++half) {
        float4 a = *(const float4*)(vsrc + half * 8);
        float4 b2 = *(const float4*)(vsrc + half * 8 + 4);
        float xs[8] = {a.x, a.y, a.z, a.w, b2.x, b2.y, b2.z, b2.w};
#pragma unroll
        for (int j = 0; j < 8; ++j)
          VtS[(qd * 16 + half * 8 + j) * KST + kr] = f2bf(xs[j]);
      }
    }
    __syncthreads();
    f32x4 sacc[4];
#pragma unroll
    for (int c = 0; c < 4; ++c) sacc[c] = (f32x4){0.f, 0.f, 0.f, 0.f};
#pragma unroll
    for (int ks = 0; ks < 2; ++ks) {
#pragma unroll
      for (int c = 0; c < 4; ++c) {
        const s16x8 bh_ = *(const s16x8*)&KhS[(c * 16 + l16) * KST + ks * 32 + quad * 8];
        const s16x8 bl_ = *(const s16x8*)&KlS[(c * 16 + l16) * KST + ks * 32 + quad * 8];
        sacc[c] = __builtin_amdgcn_mfma_f32_16x16x32_bf16(qh[ks], bh_, sacc[c], 0, 0, 0);
        sacc[c] = __builtin_amdgcn_mfma_f32_16x16x32_bf16(ql[ks], bh_, sacc[c], 0, 0, 0);
        sacc[c] = __builtin_amdgcn_mfma_f32_16x16x32_bf16(qh[ks], bl_, sacc[c], 0, 0, 0);
      }
    }
    float mx[4];
#pragma unroll
    for (int r = 0; r < 4; ++r) {
      mx[r] = sacc[0][r] * scale;
#pragma unroll
      for (int c = 1; c < 4; ++c) mx[r] = fmaxf(mx[r], sacc[c][r] * scale);
#pragma unroll
      for (int d = 1; d < 16; d <<= 1) mx[r] = fmaxf(mx[r], __shfl_xor(mx[r], d));
    }
    float al[4];
#pragma unroll
    for (int r = 0; r < 4; ++r) {
      const float mn = fmaxf(m_r[r], mx[r]);
      al[r] = __expf(m_r[r] - mn);
      m_r[r] = mn;
    }
#pragma unroll
    for (int c = 0; c < 4; ++c)
#pragma unroll
      for (int r = 0; r < 4; ++r) o_acc[c][r] *= al[r];
    float rs[4] = {0.f, 0.f, 0.f, 0.f};
#pragma unroll
    for (int c = 0; c < 4; ++c) {
#pragma unroll
      for (int r = 0; r < 4; ++r) {
        const float d = sacc[c][r] * scale - m_r[r];
        float pv = __expf(d);
        rs[r] += pv;
        if (d > -25.0f) {
          const uint32_t j = (rowlin + (uint32_t)r) * (uint32_t)Sn +
                             (uint32_t)(kbase + c * 16 + l16);
          if (!keep_bit(j)) pv = 0.0f;
        }
        PSf[(w * 16 + quad * 4 + r) * KST + c * 16 + l16] = f2bf(pv);
      }
    }
#pragma unroll
    for (int r = 0; r < 4; ++r) {
#pragma unroll
      for (int d = 1; d < 16; d <<= 1) rs[r] += __shfl_xor(rs[r], d);
      l_r[r] = l_r[r] * al[r] + rs[r];
    }
#pragma unroll
    for (int ks2 = 0; ks2 < 2; ++ks2) {
      const s16x8 pa = *(const s16x8*)&PSf[(w * 16 + l16) * KST + ks2 * 32 + quad * 8];
#pragma unroll
      for (int c = 0; c < 4; ++c) {
        const s16x8 vb = *(const s16x8*)&VtS[(c * 16 + l16) * KST + ks2 * 32 + quad * 8];
        o_acc[c] = __builtin_amdgcn_mfma_f32_16x16x32_bf16(pa, vb, o_acc[c], 0, 0, 0);
      }
    }
  }
  float inv[4];
#pragma unroll
  for (int r = 0; r < 4; ++r) inv[r] = 1.0f / (l_r[r] * 0.9f);
#pragma unroll
  for (int c = 0; c < 4; ++c)
#pragma unroll
    for (int r = 0; r < 4; ++r)
      out[(bh * Sn + (size_t)(qbase + w * 16 + quad * 4 + r)) * Dn + c * 16 + l16] =
          o_acc[c][r] * inv[r];
}

extern "C" void kernel_launch(void* const* d_in, const int* in_sizes, int n_in,
                              void* d_out, int out_size, void* d_ws, size_t ws_size,
                              hipStream_t stream) {
  const float* Q = (const float*)d_in[0];
  const float* K = (const float*)d_in[1];
  const float* V = (const float*)d_in[2];
  const int* sf = (const int*)d_in[3];
  float* out = (float*)d_out;

  constexpr size_t ARR = (size_t)Bn * Hn * Sn * Dn;  // 4,194,304 elems (8 MB bf16)
  const size_t need = 3 * ARR * sizeof(uint16_t);    // 24 MB

  if (ws_size >= need) {
    uint16_t* Khg = (uint16_t*)d_ws;
    uint16_t* Klg = Khg + ARR;
    uint16_t* Vtg = Klg + ARR;
    prep_kv<<<dim3(16, 64), NT, 0, stream>>>(K, V, Khg, Klg, Vtg);
    attn_mfma5<<<dim3(Sn / TQ, Hn, Bn), NT, 0, stream>>>(Q, Khg, Klg, Vtg, V, sf, out);
  } else {
    attn_fallback<<<dim3(Sn / 64, Hn, Bn), NT, 0, stream>>>(Q, K, V, sf, out);
  }
}

// Round 8
// 185.445 us; speedup vs baseline: 1.3324x; 1.3324x over previous
//
#include <hip/hip_runtime.h>
#include <stdint.h>
#include <math.h>

// Attention: out = dropout(softmax(8 * Q K^T)) V, B=4 H=16 S=1024 D=64 fp32.
// R8 = R7 (S^T orientation) + register diet + __launch_bounds__(NT,2).
// R7's occupancy collapsed (19.7->10.2%) from register pressure (pv/dvv 4x4
// arrays live across candidate push -> combined VGPR+AGPR > 256 -> 1 wave/EU).
// Fix: fuse softmax/push/P-store per key-block (only 4 floats live), store raw
// logit sacc in Lsv (== R7's dv+mn), threshold p > exp(-11) (same predicate).
//  - S^T = K Q^T: C-layout col = q -> per-lane softmax state, 2 shuffles/row.
//  - P: 4 consecutive keys/lane -> ds_write_b64 x8 (XOR-chunk swizzled).
//  - PV as O^T (A = Vt LDS, B = P LDS): per-lane alpha/epilogue, float4 out.
//  - Staging: prep_kv pre-splits K->(Kh,Kl) bf16 + V^T bf16, XOR-swizzled
//    tiles in d_ws; global_load_lds DMA, two-barrier single-buffer (R5 proven;
//    dyn-indexed dbuf regresses: compiler inserts vmcnt(0) before ds_read).
//  - Dropout: deferred correction (candidate list + dense threefry drain).
//    Threefry: counter-mode, bits = y0^y1 (VERIFIED R2); threshold exp(-11)
//    (skipped entries contribute <= ~1e-4 masked or not).

constexpr int Bn = 4, Hn = 16, Sn = 1024, Dn = 64;
constexpr int NT = 256;
constexpr int TQ = 128, TK = 64;
constexpr int CAP = 256;  // per-wave candidate list capacity (overflow path exact)

typedef short s16x8 __attribute__((ext_vector_type(8)));
typedef short s16x4 __attribute__((ext_vector_type(4)));
typedef float f32x4 __attribute__((ext_vector_type(4)));

__device__ __forceinline__ uint16_t f2bf(float x) {  // RNE float->bf16
  uint32_t u = __float_as_uint(x);
  return (uint16_t)((u + 0x7fffu + ((u >> 16) & 1u)) >> 16);
}
__device__ __forceinline__ float bf2f(uint16_t h) {
  return __uint_as_float(((uint32_t)h) << 16);
}

__device__ __forceinline__ void tf_round(uint32_t& x0, uint32_t& x1, const int r) {
  x0 += x1;
  x1 = (x1 << r) | (x1 >> (32 - r));
  x1 ^= x0;
}

// threefry2x32, key(42)=(0,42), counter (0, j), bits = y0^y1  [VERIFIED R2]
__device__ __noinline__ int keep_bit(uint32_t j) {
  uint32_t x0 = 0u, x1 = j;
  const uint32_t k0 = 0u, k1v = 42u;
  const uint32_t k2v = k0 ^ k1v ^ 0x1BD11BDAu;
  x0 += k0; x1 += k1v;
  tf_round(x0, x1, 13); tf_round(x0, x1, 15); tf_round(x0, x1, 26); tf_round(x0, x1, 6);
  x0 += k1v; x1 += k2v + 1u;
  tf_round(x0, x1, 17); tf_round(x0, x1, 29); tf_round(x0, x1, 16); tf_round(x0, x1, 24);
  x0 += k2v; x1 += k0 + 2u;
  tf_round(x0, x1, 13); tf_round(x0, x1, 15); tf_round(x0, x1, 26); tf_round(x0, x1, 6);
  x0 += k0; x1 += k1v + 3u;
  tf_round(x0, x1, 17); tf_round(x0, x1, 29); tf_round(x0, x1, 16); tf_round(x0, x1, 24);
  x0 += k1v; x1 += k2v + 4u;
  tf_round(x0, x1, 13); tf_round(x0, x1, 15); tf_round(x0, x1, 26); tf_round(x0, x1, 6);
  x0 += k2v; x1 += k0 + 5u;
  uint32_t bits = x0 ^ x1;
  float u = __uint_as_float((bits >> 9) | 0x3f800000u) - 1.0f;
  return u < 0.9f;
}

// ---------------- pre-pass: K split + V transpose, swizzled bf16 tiles ----------------
__global__ __launch_bounds__(NT) void prep_kv(const float* __restrict__ K,
                                              const float* __restrict__ V,
                                              uint16_t* __restrict__ Khg,
                                              uint16_t* __restrict__ Klg,
                                              uint16_t* __restrict__ Vtg) {
  __shared__ float Vl[TK][Dn + 1];
  const int t = threadIdx.x;
  const int kt = blockIdx.x;   // 0..15
  const int bh = blockIdx.y;   // 0..63
  const int r = t >> 2, qd = t & 3;
  const size_t tile = ((size_t)bh * 16 + kt) * 4096;
  const float* ksrc = K + ((size_t)bh * Sn + (size_t)(kt * TK + r)) * Dn + qd * 16;
  const float* vsrc = V + ((size_t)bh * Sn + (size_t)(kt * TK + r)) * Dn + qd * 16;

#pragma unroll
  for (int half = 0; half < 2; ++half) {
    float4 a = *(const float4*)(ksrc + half * 8);
    float4 b = *(const float4*)(ksrc + half * 8 + 4);
    float xs[8] = {a.x, a.y, a.z, a.w, b.x, b.y, b.z, b.w};
    s16x8 hv, lv;
#pragma unroll
    for (int j = 0; j < 8; ++j) {
      uint16_t hb = f2bf(xs[j]);
      hv[j] = (short)hb;
      lv[j] = (short)f2bf(xs[j] - bf2f(hb));
    }
    const int sc = (qd * 2 + half) ^ (r & 7);
    *(s16x8*)&Khg[tile + (size_t)r * 64 + sc * 8] = hv;
    *(s16x8*)&Klg[tile + (size_t)r * 64 + sc * 8] = lv;
    float4 va = *(const float4*)(vsrc + half * 8);
    float4 vb = *(const float4*)(vsrc + half * 8 + 4);
    *(float4*)&Vl[r][qd * 16 + half * 8] = va;
    *(float4*)&Vl[r][qd * 16 + half * 8 + 4] = vb;
  }
  __syncthreads();
#pragma unroll
  for (int half = 0; half < 2; ++half) {
    s16x8 ov;
#pragma unroll
    for (int j = 0; j < 8; ++j) ov[j] = (short)f2bf(Vl[qd * 16 + half * 8 + j][r]);
    const int sc = (qd * 2 + half) ^ (r & 7);
    *(s16x8*)&Vtg[tile + (size_t)r * 64 + sc * 8] = ov;
  }
}

// ---------------- main flash kernel: S^T orientation, TQ=128, reg-dieted ----------------
__global__ __launch_bounds__(NT, 2) void attn_mfma6(
    const float* __restrict__ Q, const uint16_t* __restrict__ Khg,
    const uint16_t* __restrict__ Klg, const uint16_t* __restrict__ Vtg,
    const float* __restrict__ V, const int* __restrict__ scale_ptr,
    float* __restrict__ out) {
  __shared__ uint16_t KhS[TK * Dn];      // 8 KB, unpadded (DMA dest), swizzled rows
  __shared__ uint16_t KlS[TK * Dn];
  __shared__ uint16_t VtS[TK * Dn];
  __shared__ uint16_t PS[4 * 32 * 64];   // per-wave P[q][key], XOR-chunk swizzled
  __shared__ uint32_t Lm[4][CAP];        // per-wave candidate list: (rw<<10)|key
  __shared__ float Lsv[4][CAP];          // candidate raw logit s
  __shared__ float mfin[4][32];          // per-wave final row max

  const int t = threadIdx.x;
  const int w = t >> 6;
  const int lane = t & 63;
  const int l16 = lane & 15;
  const int quad = lane >> 4;
  const int xl = l16 & 7;                // XOR swizzle key

  const int b = blockIdx.z, h = blockIdx.y;
  const int qbase = blockIdx.x * TQ;
  const int bh = b * Hn + h;
  const float qscale = (float)(*scale_ptr);
  const float pthr = 1.670170079e-5f;    // exp(-11): same predicate as dv > -11

  // per-wave DMA segment offsets (elements): wave w covers segs {2w, 2w+1}
  const int e0off = (w * 2) * 512 + lane * 8;
  const int e1off = (w * 2 + 1) * 512 + lane * 8;
  const size_t tbase = (size_t)bh * 16 * 4096;
  const int psw = w * 2048;              // per-wave PS base (elements)

  // ---- Q B-frags (pre-scaled by scale_factor): wave w owns q rows
  // qbase + w*32 + u*16 + l16;  frag layout B[n=l16][k=quad*8+j] ----
  s16x8 qh[2][2], ql[2][2];
#pragma unroll
  for (int u = 0; u < 2; ++u) {
    const int qrow = qbase + w * 32 + u * 16 + l16;
    const float* src = Q + ((size_t)bh * Sn + (size_t)qrow) * Dn;
#pragma unroll
    for (int ks = 0; ks < 2; ++ks) {
      float4 x0 = *(const float4*)(src + ks * 32 + quad * 8);
      float4 x1 = *(const float4*)(src + ks * 32 + quad * 8 + 4);
      float xv[8] = {x0.x, x0.y, x0.z, x0.w, x1.x, x1.y, x1.z, x1.w};
#pragma unroll
      for (int j = 0; j < 8; ++j) {
        const float xs = xv[j] * qscale;
        uint16_t hb = f2bf(xs);
        qh[u][ks][j] = (short)hb;
        ql[u][ks][j] = (short)f2bf(xs - bf2f(hb));
      }
    }
  }

  // per-lane softmax state: ONE q per lane per u
  float m_r[2] = {-INFINITY, -INFINITY};
  float l_r[2] = {0.0f, 0.0f};
  // O^T accumulator: o_acc[u][c][r] = O[q = u*16+l16][dv = c*16+quad*4+r]
  f32x4 o_acc[2][4];
#pragma unroll
  for (int u = 0; u < 2; ++u)
#pragma unroll
    for (int c = 0; c < 4; ++c) o_acc[u][c] = (f32x4){0.f, 0.f, 0.f, 0.f};

  const uint32_t hbase = (uint32_t)bh * (uint32_t)Sn;
  int lbase = 0;  // per-wave list fill (wave-uniform)

  for (int kt = 0; kt < Sn / TK; ++kt) {
    const int kbase = kt * TK;
    __syncthreads();  // all waves done reading prev tile's LDS

    // ---- DMA staging (single buffer; R5 proven structure) ----
    {
      const size_t tile = tbase + (size_t)kt * 4096;
      __builtin_amdgcn_global_load_lds(
          (const __attribute__((address_space(1))) uint32_t*)(Khg + tile + e0off),
          (__attribute__((address_space(3))) uint32_t*)(KhS + e0off), 16, 0, 0);
      __builtin_amdgcn_global_load_lds(
          (const __attribute__((address_space(1))) uint32_t*)(Khg + tile + e1off),
          (__attribute__((address_space(3))) uint32_t*)(KhS + e1off), 16, 0, 0);
      __builtin_amdgcn_global_load_lds(
          (const __attribute__((address_space(1))) uint32_t*)(Klg + tile + e0off),
          (__attribute__((address_space(3))) uint32_t*)(KlS + e0off), 16, 0, 0);
      __builtin_amdgcn_global_load_lds(
          (const __attribute__((address_space(1))) uint32_t*)(Klg + tile + e1off),
          (__attribute__((address_space(3))) uint32_t*)(KlS + e1off), 16, 0, 0);
      __builtin_amdgcn_global_load_lds(
          (const __attribute__((address_space(1))) uint32_t*)(Vtg + tile + e0off),
          (__attribute__((address_space(3))) uint32_t*)(VtS + e0off), 16, 0, 0);
      __builtin_amdgcn_global_load_lds(
          (const __attribute__((address_space(1))) uint32_t*)(Vtg + tile + e1off),
          (__attribute__((address_space(3))) uint32_t*)(VtS + e1off), 16, 0, 0);
    }
    __syncthreads();  // vmcnt drained -> deposits visible

    // ---- S^T = K Q^T: A = K tile (LDS), B = Q (regs), split-bf16 3-MFMA.
    // C-layout: row = key-in-tile = quad*4+r, col = q = l16; c = key-block. ----
    f32x4 sacc[2][4];
#pragma unroll
    for (int u = 0; u < 2; ++u)
#pragma unroll
      for (int c = 0; c < 4; ++c) sacc[u][c] = (f32x4){0.f, 0.f, 0.f, 0.f};
#pragma unroll
    for (int ks = 0; ks < 2; ++ks) {
#pragma unroll
      for (int c = 0; c < 4; ++c) {
        const int boff = (c * 16 + l16) * 64 + (((ks * 4 + quad) ^ xl) * 8);
        const s16x8 khv = *(const s16x8*)&KhS[boff];
        const s16x8 klv = *(const s16x8*)&KlS[boff];
#pragma unroll
        for (int u = 0; u < 2; ++u) {
          sacc[u][c] = __builtin_amdgcn_mfma_f32_16x16x32_bf16(khv, qh[u][ks], sacc[u][c], 0, 0, 0);
          sacc[u][c] = __builtin_amdgcn_mfma_f32_16x16x32_bf16(khv, ql[u][ks], sacc[u][c], 0, 0, 0);
          sacc[u][c] = __builtin_amdgcn_mfma_f32_16x16x32_bf16(klv, qh[u][ks], sacc[u][c], 0, 0, 0);
        }
      }
    }

    // ---- online softmax (per-lane row state), fused push + P store ----
#pragma unroll
    for (int u = 0; u < 2; ++u) {
      float mx = sacc[u][0][0];
#pragma unroll
      for (int c = 0; c < 4; ++c)
#pragma unroll
        for (int r = 0; r < 4; ++r) mx = fmaxf(mx, sacc[u][c][r]);
      mx = fmaxf(mx, __shfl_xor(mx, 16));
      mx = fmaxf(mx, __shfl_xor(mx, 32));  // row max over all 64 keys of tile
      const float mn = fmaxf(m_r[u], mx);
      const float al = __expf(m_r[u] - mn);  // 0 on first tile
      m_r[u] = mn;
#pragma unroll
      for (int c = 0; c < 4; ++c)
#pragma unroll
        for (int r = 0; r < 4; ++r) o_acc[u][c][r] *= al;

      const bool anyhot = __ballot(mx - mn > -11.0f) != 0ull;
      float rs = 0.0f;
#pragma unroll
      for (int c = 0; c < 4; ++c) {
        float pc[4];  // only 4 floats live at the pressure peak (reg diet)
#pragma unroll
        for (int r = 0; r < 4; ++r) {
          pc[r] = __expf(sacc[u][c][r] - mn);
          rs += pc[r];  // UNMASKED row sum (softmax normalizes before dropout)
        }
        if (anyhot) {
#pragma unroll
          for (int r = 0; r < 4; ++r) {
            const uint64_t mc = __ballot(pc[r] > pthr);
            if (mc != 0ull) {
              if (lbase + 64 <= CAP) {
                const int slot = lbase + (int)__popcll(mc & ((1ull << lane) - 1ull));
                if (pc[r] > pthr) {
                  const uint32_t rw = (uint32_t)(u * 16 + l16);
                  Lm[w][slot] = (rw << 10) | (uint32_t)(kbase + c * 16 + quad * 4 + r);
                  Lsv[w][slot] = sacc[u][c][r];  // raw logit (== dv + mn)
                }
                lbase += (int)__popcll(mc);
              } else if (pc[r] > pthr) {  // overflow: inline exact dropout
                const uint32_t j =
                    (hbase + (uint32_t)(qbase + w * 32 + u * 16 + l16)) * (uint32_t)Sn +
                    (uint32_t)(kbase + c * 16 + quad * 4 + r);
                if (!keep_bit(j)) pc[r] = 0.0f;  // rs already added (unmasked)
              }
            }
          }
        }
        // P store: 4 consecutive keys -> b64, XOR-chunk swizzled
        s16x4 pk;
#pragma unroll
        for (int r = 0; r < 4; ++r) pk[r] = (short)f2bf(pc[r]);
        const int pos = (c * 2 + (quad >> 1)) ^ xl;
        *(s16x4*)&PS[psw + (u * 16 + l16) * 64 + pos * 8 + (quad & 1) * 4] = pk;
      }

      rs += __shfl_xor(rs, 16);
      rs += __shfl_xor(rs, 32);
      l_r[u] = l_r[u] * al + rs;
    }

    // ---- PV as O^T: A = Vt (LDS), B = P (LDS, same-wave RAW) ----
#pragma unroll
    for (int ks2 = 0; ks2 < 2; ++ks2) {
      s16x8 pb[2];
#pragma unroll
      for (int u = 0; u < 2; ++u)
        pb[u] = *(const s16x8*)&PS[psw + (u * 16 + l16) * 64 + (((ks2 * 4 + quad) ^ xl) * 8)];
#pragma unroll
      for (int c = 0; c < 4; ++c) {
        const int voff = (c * 16 + l16) * 64 + (((ks2 * 4 + quad) ^ xl) * 8);
        const s16x8 vb = *(const s16x8*)&VtS[voff];
#pragma unroll
        for (int u = 0; u < 2; ++u)
          o_acc[u][c] = __builtin_amdgcn_mfma_f32_16x16x32_bf16(vb, pb[u], o_acc[u][c], 0, 0, 0);
      }
    }
  }

  // ---- drain: dense threefry over candidate list, subtract dropped p*V ----
  if (quad == 0) {
#pragma unroll
    for (int u = 0; u < 2; ++u) mfin[w][u * 16 + l16] = m_r[u];
  }
  for (int e0 = 0; e0 < lbase; e0 += 64) {
    const int e = e0 + lane;
    const bool valid = e < lbase;
    const uint32_t meta = valid ? Lm[w][e] : 0u;
    const float sv = valid ? Lsv[w][e] : 0.0f;
    const uint32_t rwv = meta >> 10, keyv = meta & 1023u;
    const uint32_t grow = (uint32_t)(qbase + w * 32) + rwv;
    const uint32_t j = (hbase + grow) * (uint32_t)Sn + keyv;
    const int kb = keep_bit(j);  // dense: all 64 lanes productive
    uint64_t dm = __ballot(valid && !kb);
    while (dm != 0ull) {
      const int src = (int)__builtin_ctzll(dm);
      dm &= dm - 1ull;
      const uint32_t meta_s = (uint32_t)__builtin_amdgcn_readlane((int)meta, src);
      const float sv_s =
          __uint_as_float((uint32_t)__builtin_amdgcn_readlane((int)__float_as_uint(sv), src));
      const int rw = (int)(meta_s >> 10);
      const int key = (int)(meta_s & 1023u);
      const float p = __expf(sv_s - mfin[w][rw]);
      const float pb2 = bf2f(f2bf(p));
      if ((rw & 15) == l16) {  // the 4 quads owning column q participate
        const float* vp = V + ((size_t)bh * Sn + (size_t)key) * Dn;
        if ((rw >> 4) == 0) {
#pragma unroll
          for (int c = 0; c < 4; ++c) {
            float4 vv = *(const float4*)(vp + c * 16 + quad * 4);
            o_acc[0][c][0] = fmaf(-pb2, bf2f(f2bf(vv.x)), o_acc[0][c][0]);
            o_acc[0][c][1] = fmaf(-pb2, bf2f(f2bf(vv.y)), o_acc[0][c][1]);
            o_acc[0][c][2] = fmaf(-pb2, bf2f(f2bf(vv.z)), o_acc[0][c][2]);
            o_acc[0][c][3] = fmaf(-pb2, bf2f(f2bf(vv.w)), o_acc[0][c][3]);
          }
        } else {
#pragma unroll
          for (int c = 0; c < 4; ++c) {
            float4 vv = *(const float4*)(vp + c * 16 + quad * 4);
            o_acc[1][c][0] = fmaf(-pb2, bf2f(f2bf(vv.x)), o_acc[1][c][0]);
            o_acc[1][c][1] = fmaf(-pb2, bf2f(f2bf(vv.y)), o_acc[1][c][1]);
            o_acc[1][c][2] = fmaf(-pb2, bf2f(f2bf(vv.z)), o_acc[1][c][2]);
            o_acc[1][c][3] = fmaf(-pb2, bf2f(f2bf(vv.w)), o_acc[1][c][3]);
          }
        }
      }
    }
  }

  // ---- epilogue: out[q][dv] = O^T / (l * 0.9); per-lane scalar scale ----
#pragma unroll
  for (int u = 0; u < 2; ++u) {
    const float inv = 1.0f / (l_r[u] * 0.9f);
    const size_t obase = ((size_t)bh * Sn + (size_t)(qbase + w * 32 + u * 16 + l16)) * Dn;
#pragma unroll
    for (int c = 0; c < 4; ++c) {
      float4 ov;
      ov.x = o_acc[u][c][0] * inv;
      ov.y = o_acc[u][c][1] * inv;
      ov.z = o_acc[u][c][2] * inv;
      ov.w = o_acc[u][c][3] * inv;
      *(float4*)(out + obase + c * 16 + quad * 4) = ov;
    }
  }
}

// ---------------- fallback (R3 kernel, verbatim): used only if ws too small ----------------
constexpr int KST = 72;
__global__ __launch_bounds__(NT) void attn_fallback(
    const float* __restrict__ Q, const float* __restrict__ K,
    const float* __restrict__ V, const int* __restrict__ scale_ptr,
    float* __restrict__ out) {
  __shared__ uint16_t KhS[64 * KST];
  __shared__ uint16_t KlS[64 * KST];
  __shared__ uint16_t VtS[Dn * KST];
  __shared__ uint16_t PSf[4 * 16 * KST];

  const int t = threadIdx.x;
  const int w = t >> 6;
  const int lane = t & 63;
  const int l16 = lane & 15;
  const int quad = lane >> 4;
  const int b = blockIdx.z, h = blockIdx.y;
  const int qbase = blockIdx.x * 64;
  const size_t bh = (size_t)b * Hn + h;
  const float scale = (float)(*scale_ptr);
  const float* Kp = K + bh * Sn * Dn;
  const float* Vp = V + bh * Sn * Dn;

  const int qrow = qbase + w * 16 + l16;
  const float* Qp = Q + (bh * Sn + (size_t)qrow) * Dn;
  s16x8 qh[2], ql[2];
#pragma unroll
  for (int ks = 0; ks < 2; ++ks) {
    const float* src = Qp + ks * 32 + quad * 8;
    float4 x0 = *(const float4*)(src);
    float4 x1 = *(const float4*)(src + 4);
    float xv[8] = {x0.x, x0.y, x0.z, x0.w, x1.x, x1.y, x1.z, x1.w};
#pragma unroll
    for (int j = 0; j < 8; ++j) {
      uint16_t hb = f2bf(xv[j]);
      qh[ks][j] = (short)hb;
      ql[ks][j] = (short)f2bf(xv[j] - bf2f(hb));
    }
  }
  const int kr = t >> 2;
  const int qd = t & 3;
  float m_r[4], l_r[4];
#pragma unroll
  for (int r = 0; r < 4; ++r) { m_r[r] = -INFINITY; l_r[r] = 0.0f; }
  f32x4 o_acc[4];
#pragma unroll
  for (int c = 0; c < 4; ++c) o_acc[c] = (f32x4){0.f, 0.f, 0.f, 0.f};
  const uint32_t rowlin = ((uint32_t)(b * Hn + h)) * (uint32_t)Sn +
                          (uint32_t)(qbase + w * 16 + quad * 4);
  for (int kt = 0; kt < Sn / 64; ++kt) {
    const int kbase = kt * 64;
    __syncthreads();
    {
      const float* ksrc = Kp + (size_t)(kbase + kr) * Dn + qd * 16;
#pragma unroll
      for (int half = 0; half < 2; ++half) {
        float4 a = *(const float4*)(ksrc + half * 8);
        float4 b2 = *(const float4*)(ksrc + half * 8 + 4);
        float xs[8] = {a.x, a.y, a.z, a.w, b2.x, b2.y, b2.z, b2.w};
        s16x8 hv, lv;
#pragma unroll
        for (int j = 0; j < 8; ++j) {
          uint16_t hb = f2bf(xs[j]);
          hv[j] = (short)hb;
          lv[j] = (short)f2bf(xs[j] - bf2f(hb));
        }
        *(s16x8*)&KhS[kr * KST + qd * 16 + half * 8] = hv;
        *(s16x8*)&KlS[kr * KST + qd * 16 + half * 8] = lv;
      }
      const float* vsrc = Vp + (size_t)(kbase + kr) * Dn + qd * 16;
#pragma unroll
      for (int half = 0; half < 2; ++half) {
        float4 a = *(const float4*)(vsrc + half * 8);
        float4 b2 = *(const float4*)(vsrc + half * 8 + 4);
        float xs[8] = {a.x, a.y, a.z, a.w, b2.x, b2.y, b2.z, b2.w};
#pragma unroll
        for (int j = 0; j < 8; ++j)
          VtS[(qd * 16 + half * 8 + j) * KST + kr] = f2bf(xs[j]);
      }
    }
    __syncthreads();
    f32x4 sacc[4];
#pragma unroll
    for (int c = 0; c < 4; ++c) sacc[c] = (f32x4){0.f, 0.f, 0.f, 0.f};
#pragma unroll
    for (int ks = 0; ks < 2; ++ks) {
#pragma unroll
      for (int c = 0; c < 4; ++c) {
        const s16x8 bh_ = *(const s16x8*)&KhS[(c * 16 + l16) * KST + ks * 32 + quad * 8];
        const s16x8 bl_ = *(const s16x8*)&KlS[(c * 16 + l16) * KST + ks * 32 + quad * 8];
        sacc[c] = __builtin_amdgcn_mfma_f32_16x16x32_bf16(qh[ks], bh_, sacc[c], 0, 0, 0);
        sacc[c] = __builtin_amdgcn_mfma_f32_16x16x32_bf16(ql[ks], bh_, sacc[c], 0, 0, 0);
        sacc[c] = __builtin_amdgcn_mfma_f32_16x16x32_bf16(qh[ks], bl_, sacc[c], 0, 0, 0);
      }
    }
    float mx[4];
#pragma unroll
    for (int r = 0; r < 4; ++r) {
      mx[r] = sacc[0][r] * scale;
#pragma unroll
      for (int c = 1; c < 4; ++c) mx[r] = fmaxf(mx[r], sacc[c][r] * scale);
#pragma unroll
      for (int d = 1; d < 16; d <<= 1) mx[r] = fmaxf(mx[r], __shfl_xor(mx[r], d));
    }
    float al[4];
#pragma unroll
    for (int r = 0; r < 4; ++r) {
      const float mn = fmaxf(m_r[r], mx[r]);
      al[r] = __expf(m_r[r] - mn);
      m_r[r] = mn;
    }
#pragma unroll
    for (int c = 0; c < 4; ++c)
#pragma unroll
      for (int r = 0; r < 4; ++r) o_acc[c][r] *= al[r];
    float rs[4] = {0.f, 0.f, 0.f, 0.f};
#pragma unroll
    for (int c = 0; c < 4; ++c) {
#pragma unroll
      for (int r = 0; r < 4; ++r) {
        const float d = sacc[c][r] * scale - m_r[r];
        float pv = __expf(d);
        rs[r] += pv;
        if (d > -25.0f) {
          const uint32_t j = (rowlin + (uint32_t)r) * (uint32_t)Sn +
                             (uint32_t)(kbase + c * 16 + l16);
          if (!keep_bit(j)) pv = 0.0f;
        }
        PSf[(w * 16 + quad * 4 + r) * KST + c * 16 + l16] = f2bf(pv);
      }
    }
#pragma unroll
    for (int r = 0; r < 4; ++r) {
#pragma unroll
      for (int d = 1; d < 16; d <<= 1) rs[r] += __shfl_xor(rs[r], d);
      l_r[r] = l_r[r] * al[r] + rs[r];
    }
#pragma unroll
    for (int ks2 = 0; ks2 < 2; ++ks2) {
      const s16x8 pa = *(const s16x8*)&PSf[(w * 16 + l16) * KST + ks2 * 32 + quad * 8];
#pragma unroll
      for (int c = 0; c < 4; ++c) {
        const s16x8 vb = *(const s16x8*)&VtS[(c * 16 + l16) * KST + ks2 * 32 + quad * 8];
        o_acc[c] = __builtin_amdgcn_mfma_f32_16x16x32_bf16(pa, vb, o_acc[c], 0, 0, 0);
      }
    }
  }
  float inv[4];
#pragma unroll
  for (int r = 0; r < 4; ++r) inv[r] = 1.0f / (l_r[r] * 0.9f);
#pragma unroll
  for (int c = 0; c < 4; ++c)
#pragma unroll
    for (int r = 0; r < 4; ++r)
      out[(bh * Sn + (size_t)(qbase + w * 16 + quad * 4 + r)) * Dn + c * 16 + l16] =
          o_acc[c][r] * inv[r];
}

extern "C" void kernel_launch(void* const* d_in, const int* in_sizes, int n_in,
                              void* d_out, int out_size, void* d_ws, size_t ws_size,
                              hipStream_t stream) {
  const float* Q = (const float*)d_in[0];
  const float* K = (const float*)d_in[1];
  const float* V = (const float*)d_in[2];
  const int* sf = (const int*)d_in[3];
  float* out = (float*)d_out;

  constexpr size_t ARR = (size_t)Bn * Hn * Sn * Dn;  // 4,194,304 elems (8 MB bf16)
  const size_t need = 3 * ARR * sizeof(uint16_t);    // 24 MB

  if (ws_size >= need) {
    uint16_t* Khg = (uint16_t*)d_ws;
    uint16_t* Klg = Khg + ARR;
    uint16_t* Vtg = Klg + ARR;
    prep_kv<<<dim3(16, 64), NT, 0, stream>>>(K, V, Khg, Klg, Vtg);
    attn_mfma6<<<dim3(Sn / TQ, Hn, Bn), NT, 0, stream>>>(Q, Khg, Klg, Vtg, V, sf, out);
  } else {
    attn_fallback<<<dim3(Sn / 64, Hn, Bn), NT, 0, stream>>>(Q, K, V, sf, out);
  }
}

// Round 9
// 169.516 us; speedup vs baseline: 1.4576x; 1.0940x over previous
//
#include <hip/hip_runtime.h>
#include <stdint.h>
#include <math.h>

// Attention: out = dropout(softmax(8 * Q K^T)) V, B=4 H=16 S=1024 D=64 fp32.
// R9 = R8 (S^T orientation, reg-dieted) with TQ 128->64: grid 512->1024 blocks
// -> 4 blocks/CU (was residency-capped at 2 by the grid). All pipes were <32%
// busy at R8 => latency-bound; doubling co-resident waves (8->16/CU) lets
// inter-block overlap hide DMA drain + dependency chains. Total MFMA/VALU work
// unchanged; DS/DMA totals double but stay under the new wall.
//  - S^T = K Q^T: C-layout col = q -> per-lane softmax state, 2 shuffles/row.
//  - P: 4 consecutive keys/lane -> ds_write_b64 x4 (XOR-chunk swizzled).
//  - PV as O^T (A = Vt LDS, B = P LDS): per-lane alpha/epilogue, float4 out.
//  - Staging: prep_kv pre-splits K->(Kh,Kl) bf16 + V^T bf16, XOR-swizzled
//    tiles in d_ws; global_load_lds DMA, two-barrier single-buffer (R5/R8
//    proven; dyn-indexed dbuf regresses: compiler vmcnt(0) before ds_read).
//  - Dropout: deferred correction (candidate list + dense threefry drain).
//    Threefry: counter-mode, bits = y0^y1 (VERIFIED R2); threshold exp(-11)
//    (skipped entries contribute <= ~1e-4 masked or not).

constexpr int Bn = 4, Hn = 16, Sn = 1024, Dn = 64;
constexpr int NT = 256;
constexpr int TK = 64;
constexpr int TQM = 64;   // main-kernel q tile (wave w owns q rows w*16..w*16+15)
constexpr int CAP = 128;  // per-wave candidate list capacity (overflow path exact)

typedef short s16x8 __attribute__((ext_vector_type(8)));
typedef short s16x4 __attribute__((ext_vector_type(4)));
typedef float f32x4 __attribute__((ext_vector_type(4)));

__device__ __forceinline__ uint16_t f2bf(float x) {  // RNE float->bf16
  uint32_t u = __float_as_uint(x);
  return (uint16_t)((u + 0x7fffu + ((u >> 16) & 1u)) >> 16);
}
__device__ __forceinline__ float bf2f(uint16_t h) {
  return __uint_as_float(((uint32_t)h) << 16);
}

__device__ __forceinline__ void tf_round(uint32_t& x0, uint32_t& x1, const int r) {
  x0 += x1;
  x1 = (x1 << r) | (x1 >> (32 - r));
  x1 ^= x0;
}

// threefry2x32, key(42)=(0,42), counter (0, j), bits = y0^y1  [VERIFIED R2]
__device__ __noinline__ int keep_bit(uint32_t j) {
  uint32_t x0 = 0u, x1 = j;
  const uint32_t k0 = 0u, k1v = 42u;
  const uint32_t k2v = k0 ^ k1v ^ 0x1BD11BDAu;
  x0 += k0; x1 += k1v;
  tf_round(x0, x1, 13); tf_round(x0, x1, 15); tf_round(x0, x1, 26); tf_round(x0, x1, 6);
  x0 += k1v; x1 += k2v + 1u;
  tf_round(x0, x1, 17); tf_round(x0, x1, 29); tf_round(x0, x1, 16); tf_round(x0, x1, 24);
  x0 += k2v; x1 += k0 + 2u;
  tf_round(x0, x1, 13); tf_round(x0, x1, 15); tf_round(x0, x1, 26); tf_round(x0, x1, 6);
  x0 += k0; x1 += k1v + 3u;
  tf_round(x0, x1, 17); tf_round(x0, x1, 29); tf_round(x0, x1, 16); tf_round(x0, x1, 24);
  x0 += k1v; x1 += k2v + 4u;
  tf_round(x0, x1, 13); tf_round(x0, x1, 15); tf_round(x0, x1, 26); tf_round(x0, x1, 6);
  x0 += k2v; x1 += k0 + 5u;
  uint32_t bits = x0 ^ x1;
  float u = __uint_as_float((bits >> 9) | 0x3f800000u) - 1.0f;
  return u < 0.9f;
}

// ---------------- pre-pass: K split + V transpose, swizzled bf16 tiles ----------------
__global__ __launch_bounds__(NT) void prep_kv(const float* __restrict__ K,
                                              const float* __restrict__ V,
                                              uint16_t* __restrict__ Khg,
                                              uint16_t* __restrict__ Klg,
                                              uint16_t* __restrict__ Vtg) {
  __shared__ float Vl[TK][Dn + 1];
  const int t = threadIdx.x;
  const int kt = blockIdx.x;   // 0..15
  const int bh = blockIdx.y;   // 0..63
  const int r = t >> 2, qd = t & 3;
  const size_t tile = ((size_t)bh * 16 + kt) * 4096;
  const float* ksrc = K + ((size_t)bh * Sn + (size_t)(kt * TK + r)) * Dn + qd * 16;
  const float* vsrc = V + ((size_t)bh * Sn + (size_t)(kt * TK + r)) * Dn + qd * 16;

#pragma unroll
  for (int half = 0; half < 2; ++half) {
    float4 a = *(const float4*)(ksrc + half * 8);
    float4 b = *(const float4*)(ksrc + half * 8 + 4);
    float xs[8] = {a.x, a.y, a.z, a.w, b.x, b.y, b.z, b.w};
    s16x8 hv, lv;
#pragma unroll
    for (int j = 0; j < 8; ++j) {
      uint16_t hb = f2bf(xs[j]);
      hv[j] = (short)hb;
      lv[j] = (short)f2bf(xs[j] - bf2f(hb));
    }
    const int sc = (qd * 2 + half) ^ (r & 7);
    *(s16x8*)&Khg[tile + (size_t)r * 64 + sc * 8] = hv;
    *(s16x8*)&Klg[tile + (size_t)r * 64 + sc * 8] = lv;
    float4 va = *(const float4*)(vsrc + half * 8);
    float4 vb = *(const float4*)(vsrc + half * 8 + 4);
    *(float4*)&Vl[r][qd * 16 + half * 8] = va;
    *(float4*)&Vl[r][qd * 16 + half * 8 + 4] = vb;
  }
  __syncthreads();
#pragma unroll
  for (int half = 0; half < 2; ++half) {
    s16x8 ov;
#pragma unroll
    for (int j = 0; j < 8; ++j) ov[j] = (short)f2bf(Vl[qd * 16 + half * 8 + j][r]);
    const int sc = (qd * 2 + half) ^ (r & 7);
    *(s16x8*)&Vtg[tile + (size_t)r * 64 + sc * 8] = ov;
  }
}

// ---------------- main flash kernel: S^T orientation, TQ=64, 4 blocks/CU ----------------
__global__ __launch_bounds__(NT, 4) void attn_mfma7(
    const float* __restrict__ Q, const uint16_t* __restrict__ Khg,
    const uint16_t* __restrict__ Klg, const uint16_t* __restrict__ Vtg,
    const float* __restrict__ V, const int* __restrict__ scale_ptr,
    float* __restrict__ out) {
  __shared__ uint16_t KhS[TK * Dn];      // 8 KB, unpadded (DMA dest), swizzled rows
  __shared__ uint16_t KlS[TK * Dn];
  __shared__ uint16_t VtS[TK * Dn];
  __shared__ uint16_t PS[4 * 16 * 64];   // per-wave P[q][key], XOR-chunk swizzled
  __shared__ uint32_t Lm[4][CAP];        // per-wave candidate list: (rw<<10)|key
  __shared__ float Lsv[4][CAP];          // candidate raw logit s
  __shared__ float mfin[4][16];          // per-wave final row max

  const int t = threadIdx.x;
  const int w = t >> 6;
  const int lane = t & 63;
  const int l16 = lane & 15;
  const int quad = lane >> 4;
  const int xl = l16 & 7;                // XOR swizzle key

  const int b = blockIdx.z, h = blockIdx.y;
  const int qbase = blockIdx.x * TQM;
  const int bh = b * Hn + h;
  const float qscale = (float)(*scale_ptr);
  const float pthr = 1.670170079e-5f;    // exp(-11)

  // per-wave DMA segment offsets (elements): wave w covers segs {2w, 2w+1}
  const int e0off = (w * 2) * 512 + lane * 8;
  const int e1off = (w * 2 + 1) * 512 + lane * 8;
  const size_t tbase = (size_t)bh * 16 * 4096;
  const int psw = w * 1024;              // per-wave PS base (elements)

  // ---- Q B-frags (pre-scaled): wave w owns q rows qbase + w*16 + l16 ----
  s16x8 qh[2], ql[2];
  {
    const int qrow = qbase + w * 16 + l16;
    const float* src = Q + ((size_t)bh * Sn + (size_t)qrow) * Dn;
#pragma unroll
    for (int ks = 0; ks < 2; ++ks) {
      float4 x0 = *(const float4*)(src + ks * 32 + quad * 8);
      float4 x1 = *(const float4*)(src + ks * 32 + quad * 8 + 4);
      float xv[8] = {x0.x, x0.y, x0.z, x0.w, x1.x, x1.y, x1.z, x1.w};
#pragma unroll
      for (int j = 0; j < 8; ++j) {
        const float xs = xv[j] * qscale;
        uint16_t hb = f2bf(xs);
        qh[ks][j] = (short)hb;
        ql[ks][j] = (short)f2bf(xs - bf2f(hb));
      }
    }
  }

  // per-lane softmax state: ONE q per lane
  float m_r = -INFINITY, l_r = 0.0f;
  // O^T accumulator: o_acc[c][r] = O[q = l16][dv = c*16+quad*4+r]
  f32x4 o_acc[4];
#pragma unroll
  for (int c = 0; c < 4; ++c) o_acc[c] = (f32x4){0.f, 0.f, 0.f, 0.f};

  const uint32_t hbase = (uint32_t)bh * (uint32_t)Sn;
  int lbase = 0;  // per-wave list fill (wave-uniform)

  for (int kt = 0; kt < Sn / TK; ++kt) {
    const int kbase = kt * TK;
    __syncthreads();  // all waves done reading prev tile's LDS

    // ---- DMA staging (single buffer; R5/R8 proven structure) ----
    {
      const size_t tile = tbase + (size_t)kt * 4096;
      __builtin_amdgcn_global_load_lds(
          (const __attribute__((address_space(1))) uint32_t*)(Khg + tile + e0off),
          (__attribute__((address_space(3))) uint32_t*)(KhS + e0off), 16, 0, 0);
      __builtin_amdgcn_global_load_lds(
          (const __attribute__((address_space(1))) uint32_t*)(Khg + tile + e1off),
          (__attribute__((address_space(3))) uint32_t*)(KhS + e1off), 16, 0, 0);
      __builtin_amdgcn_global_load_lds(
          (const __attribute__((address_space(1))) uint32_t*)(Klg + tile + e0off),
          (__attribute__((address_space(3))) uint32_t*)(KlS + e0off), 16, 0, 0);
      __builtin_amdgcn_global_load_lds(
          (const __attribute__((address_space(1))) uint32_t*)(Klg + tile + e1off),
          (__attribute__((address_space(3))) uint32_t*)(KlS + e1off), 16, 0, 0);
      __builtin_amdgcn_global_load_lds(
          (const __attribute__((address_space(1))) uint32_t*)(Vtg + tile + e0off),
          (__attribute__((address_space(3))) uint32_t*)(VtS + e0off), 16, 0, 0);
      __builtin_amdgcn_global_load_lds(
          (const __attribute__((address_space(1))) uint32_t*)(Vtg + tile + e1off),
          (__attribute__((address_space(3))) uint32_t*)(VtS + e1off), 16, 0, 0);
    }
    __syncthreads();  // vmcnt drained -> deposits visible

    // ---- S^T = K Q^T: A = K tile (LDS), B = Q (regs), split-bf16 3-MFMA.
    // C-layout: row = key-in-tile = quad*4+r, col = q = l16; c = key-block. ----
    f32x4 sacc[4];
#pragma unroll
    for (int c = 0; c < 4; ++c) sacc[c] = (f32x4){0.f, 0.f, 0.f, 0.f};
#pragma unroll
    for (int ks = 0; ks < 2; ++ks) {
#pragma unroll
      for (int c = 0; c < 4; ++c) {
        const int boff = (c * 16 + l16) * 64 + (((ks * 4 + quad) ^ xl) * 8);
        const s16x8 khv = *(const s16x8*)&KhS[boff];
        const s16x8 klv = *(const s16x8*)&KlS[boff];
        sacc[c] = __builtin_amdgcn_mfma_f32_16x16x32_bf16(khv, qh[ks], sacc[c], 0, 0, 0);
        sacc[c] = __builtin_amdgcn_mfma_f32_16x16x32_bf16(khv, ql[ks], sacc[c], 0, 0, 0);
        sacc[c] = __builtin_amdgcn_mfma_f32_16x16x32_bf16(klv, qh[ks], sacc[c], 0, 0, 0);
      }
    }

    // ---- online softmax (per-lane row state), fused push + P store ----
    {
      float mx = sacc[0][0];
#pragma unroll
      for (int c = 0; c < 4; ++c)
#pragma unroll
        for (int r = 0; r < 4; ++r) mx = fmaxf(mx, sacc[c][r]);
      mx = fmaxf(mx, __shfl_xor(mx, 16));
      mx = fmaxf(mx, __shfl_xor(mx, 32));  // row max over all 64 keys of tile
      const float mn = fmaxf(m_r, mx);
      const float al = __expf(m_r - mn);   // 0 on first tile
      m_r = mn;
#pragma unroll
      for (int c = 0; c < 4; ++c)
#pragma unroll
        for (int r = 0; r < 4; ++r) o_acc[c][r] *= al;

      const bool anyhot = __ballot(mx - mn > -11.0f) != 0ull;
      float rs = 0.0f;
#pragma unroll
      for (int c = 0; c < 4; ++c) {
        float pc[4];  // only 4 floats live at the pressure peak (reg diet)
#pragma unroll
        for (int r = 0; r < 4; ++r) {
          pc[r] = __expf(sacc[c][r] - mn);
          rs += pc[r];  // UNMASKED row sum (softmax normalizes before dropout)
        }
        if (anyhot) {
#pragma unroll
          for (int r = 0; r < 4; ++r) {
            const uint64_t mc = __ballot(pc[r] > pthr);
            if (mc != 0ull) {
              if (lbase + 64 <= CAP) {
                const int slot = lbase + (int)__popcll(mc & ((1ull << lane) - 1ull));
                if (pc[r] > pthr) {
                  Lm[w][slot] = ((uint32_t)l16 << 10) |
                                (uint32_t)(kbase + c * 16 + quad * 4 + r);
                  Lsv[w][slot] = sacc[c][r];  // raw logit
                }
                lbase += (int)__popcll(mc);
              } else if (pc[r] > pthr) {  // overflow: inline exact dropout
                const uint32_t j =
                    (hbase + (uint32_t)(qbase + w * 16 + l16)) * (uint32_t)Sn +
                    (uint32_t)(kbase + c * 16 + quad * 4 + r);
                if (!keep_bit(j)) pc[r] = 0.0f;  // rs already added (unmasked)
              }
            }
          }
        }
        // P store: 4 consecutive keys -> b64, XOR-chunk swizzled
        s16x4 pk;
#pragma unroll
        for (int r = 0; r < 4; ++r) pk[r] = (short)f2bf(pc[r]);
        const int pos = (c * 2 + (quad >> 1)) ^ xl;
        *(s16x4*)&PS[psw + l16 * 64 + pos * 8 + (quad & 1) * 4] = pk;
      }

      rs += __shfl_xor(rs, 16);
      rs += __shfl_xor(rs, 32);
      l_r = l_r * al + rs;
    }

    // ---- PV as O^T: A = Vt (LDS), B = P (LDS, same-wave RAW) ----
#pragma unroll
    for (int ks2 = 0; ks2 < 2; ++ks2) {
      const s16x8 pb = *(const s16x8*)&PS[psw + l16 * 64 + (((ks2 * 4 + quad) ^ xl) * 8)];
#pragma unroll
      for (int c = 0; c < 4; ++c) {
        const int voff = (c * 16 + l16) * 64 + (((ks2 * 4 + quad) ^ xl) * 8);
        const s16x8 vb = *(const s16x8*)&VtS[voff];
        o_acc[c] = __builtin_amdgcn_mfma_f32_16x16x32_bf16(vb, pb, o_acc[c], 0, 0, 0);
      }
    }
  }

  // ---- drain: dense threefry over candidate list, subtract dropped p*V ----
  if (quad == 0) mfin[w][l16] = m_r;
  for (int e0 = 0; e0 < lbase; e0 += 64) {
    const int e = e0 + lane;
    const bool valid = e < lbase;
    const uint32_t meta = valid ? Lm[w][e] : 0u;
    const float sv = valid ? Lsv[w][e] : 0.0f;
    const uint32_t rwv = meta >> 10, keyv = meta & 1023u;
    const uint32_t grow = (uint32_t)(qbase + w * 16) + rwv;
    const uint32_t j = (hbase + grow) * (uint32_t)Sn + keyv;
    const int kb = keep_bit(j);  // dense: all 64 lanes productive
    uint64_t dm = __ballot(valid && !kb);
    while (dm != 0ull) {
      const int src = (int)__builtin_ctzll(dm);
      dm &= dm - 1ull;
      const uint32_t meta_s = (uint32_t)__builtin_amdgcn_readlane((int)meta, src);
      const float sv_s =
          __uint_as_float((uint32_t)__builtin_amdgcn_readlane((int)__float_as_uint(sv), src));
      const int rw = (int)(meta_s >> 10);
      const int key = (int)(meta_s & 1023u);
      const float p = __expf(sv_s - mfin[w][rw]);
      const float pb2 = bf2f(f2bf(p));
      if (rw == l16) {  // the 4 quads owning column q participate
        const float* vp = V + ((size_t)bh * Sn + (size_t)key) * Dn;
#pragma unroll
        for (int c = 0; c < 4; ++c) {
          float4 vv = *(const float4*)(vp + c * 16 + quad * 4);
          o_acc[c][0] = fmaf(-pb2, bf2f(f2bf(vv.x)), o_acc[c][0]);
          o_acc[c][1] = fmaf(-pb2, bf2f(f2bf(vv.y)), o_acc[c][1]);
          o_acc[c][2] = fmaf(-pb2, bf2f(f2bf(vv.z)), o_acc[c][2]);
          o_acc[c][3] = fmaf(-pb2, bf2f(f2bf(vv.w)), o_acc[c][3]);
        }
      }
    }
  }

  // ---- epilogue: out[q][dv] = O^T / (l * 0.9); per-lane scalar scale ----
  {
    const float inv = 1.0f / (l_r * 0.9f);
    const size_t obase = ((size_t)bh * Sn + (size_t)(qbase + w * 16 + l16)) * Dn;
#pragma unroll
    for (int c = 0; c < 4; ++c) {
      float4 ov;
      ov.x = o_acc[c][0] * inv;
      ov.y = o_acc[c][1] * inv;
      ov.z = o_acc[c][2] * inv;
      ov.w = o_acc[c][3] * inv;
      *(float4*)(out + obase + c * 16 + quad * 4) = ov;
    }
  }
}

// ---------------- fallback (R3 kernel, verbatim): used only if ws too small ----------------
constexpr int KST = 72;
__global__ __launch_bounds__(NT) void attn_fallback(
    const float* __restrict__ Q, const float* __restrict__ K,
    const float* __restrict__ V, const int* __restrict__ scale_ptr,
    float* __restrict__ out) {
  __shared__ uint16_t KhS[64 * KST];
  __shared__ uint16_t KlS[64 * KST];
  __shared__ uint16_t VtS[Dn * KST];
  __shared__ uint16_t PSf[4 * 16 * KST];

  const int t = threadIdx.x;
  const int w = t >> 6;
  const int lane = t & 63;
  const int l16 = lane & 15;
  const int quad = lane >> 4;
  const int b = blockIdx.z, h = blockIdx.y;
  const int qbase = blockIdx.x * 64;
  const size_t bh = (size_t)b * Hn + h;
  const float scale = (float)(*scale_ptr);
  const float* Kp = K + bh * Sn * Dn;
  const float* Vp = V + bh * Sn * Dn;

  const int qrow = qbase + w * 16 + l16;
  const float* Qp = Q + (bh * Sn + (size_t)qrow) * Dn;
  s16x8 qh[2], ql[2];
#pragma unroll
  for (int ks = 0; ks < 2; ++ks) {
    const float* src = Qp + ks * 32 + quad * 8;
    float4 x0 = *(const float4*)(src);
    float4 x1 = *(const float4*)(src + 4);
    float xv[8] = {x0.x, x0.y, x0.z, x0.w, x1.x, x1.y, x1.z, x1.w};
#pragma unroll
    for (int j = 0; j < 8; ++j) {
      uint16_t hb = f2bf(xv[j]);
      qh[ks][j] = (short)hb;
      ql[ks][j] = (short)f2bf(xv[j] - bf2f(hb));
    }
  }
  const int kr = t >> 2;
  const int qd = t & 3;
  float m_r[4], l_r[4];
#pragma unroll
  for (int r = 0; r < 4; ++r) { m_r[r] = -INFINITY; l_r[r] = 0.0f; }
  f32x4 o_acc[4];
#pragma unroll
  for (int c = 0; c < 4; ++c) o_acc[c] = (f32x4){0.f, 0.f, 0.f, 0.f};
  const uint32_t rowlin = ((uint32_t)(b * Hn + h)) * (uint32_t)Sn +
                          (uint32_t)(qbase + w * 16 + quad * 4);
  for (int kt = 0; kt < Sn / 64; ++kt) {
    const int kbase = kt * 64;
    __syncthreads();
    {
      const float* ksrc = Kp + (size_t)(kbase + kr) * Dn + qd * 16;
#pragma unroll
      for (int half = 0; half < 2; ++half) {
        float4 a = *(const float4*)(ksrc + half * 8);
        float4 b2 = *(const float4*)(ksrc + half * 8 + 4);
        float xs[8] = {a.x, a.y, a.z, a.w, b2.x, b2.y, b2.z, b2.w};
        s16x8 hv, lv;
#pragma unroll
        for (int j = 0; j < 8; ++j) {
          uint16_t hb = f2bf(xs[j]);
          hv[j] = (short)hb;
          lv[j] = (short)f2bf(xs[j] - bf2f(hb));
        }
        *(s16x8*)&KhS[kr * KST + qd * 16 + half * 8] = hv;
        *(s16x8*)&KlS[kr * KST + qd * 16 + half * 8] = lv;
      }
      const float* vsrc = Vp + (size_t)(kbase + kr) * Dn + qd * 16;
#pragma unroll
      for (int half = 0; half < 2; ++half) {
        float4 a = *(const float4*)(vsrc + half * 8);
        float4 b2 = *(const float4*)(vsrc + half * 8 + 4);
        float xs[8] = {a.x, a.y, a.z, a.w, b2.x, b2.y, b2.z, b2.w};
#pragma unroll
        for (int j = 0; j < 8; ++j)
          VtS[(qd * 16 + half * 8 + j) * KST + kr] = f2bf(xs[j]);
      }
    }
    __syncthreads();
    f32x4 sacc[4];
#pragma unroll
    for (int c = 0; c < 4; ++c) sacc[c] = (f32x4){0.f, 0.f, 0.f, 0.f};
#pragma unroll
    for (int ks = 0; ks < 2; ++ks) {
#pragma unroll
      for (int c = 0; c < 4; ++c) {
        const s16x8 bh_ = *(const s16x8*)&KhS[(c * 16 + l16) * KST + ks * 32 + quad * 8];
        const s16x8 bl_ = *(const s16x8*)&KlS[(c * 16 + l16) * KST + ks * 32 + quad * 8];
        sacc[c] = __builtin_amdgcn_mfma_f32_16x16x32_bf16(qh[ks], bh_, sacc[c], 0, 0, 0);
        sacc[c] = __builtin_amdgcn_mfma_f32_16x16x32_bf16(ql[ks], bh_, sacc[c], 0, 0, 0);
        sacc[c] = __builtin_amdgcn_mfma_f32_16x16x32_bf16(qh[ks], bl_, sacc[c], 0, 0, 0);
      }
    }
    float mx[4];
#pragma unroll
    for (int r = 0; r < 4; ++r) {
      mx[r] = sacc[0][r] * scale;
#pragma unroll
      for (int c = 1; c < 4; ++c) mx[r] = fmaxf(mx[r], sacc[c][r] * scale);
#pragma unroll
      for (int d = 1; d < 16; d <<= 1) mx[r] = fmaxf(mx[r], __shfl_xor(mx[r], d));
    }
    float al[4];
#pragma unroll
    for (int r = 0; r < 4; ++r) {
      const float mn = fmaxf(m_r[r], mx[r]);
      al[r] = __expf(m_r[r] - mn);
      m_r[r] = mn;
    }
#pragma unroll
    for (int c = 0; c < 4; ++c)
#pragma unroll
      for (int r = 0; r < 4; ++r) o_acc[c][r] *= al[r];
    float rs[4] = {0.f, 0.f, 0.f, 0.f};
#pragma unroll
    for (int c = 0; c < 4; ++c) {
#pragma unroll
      for (int r = 0; r < 4; ++r) {
        const float d = sacc[c][r] * scale - m_r[r];
        float pv = __expf(d);
        rs[r] += pv;
        if (d > -25.0f) {
          const uint32_t j = (rowlin + (uint32_t)r) * (uint32_t)Sn +
                             (uint32_t)(kbase + c * 16 + l16);
          if (!keep_bit(j)) pv = 0.0f;
        }
        PSf[(w * 16 + quad * 4 + r) * KST + c * 16 + l16] = f2bf(pv);
      }
    }
#pragma unroll
    for (int r = 0; r < 4; ++r) {
#pragma unroll
      for (int d = 1; d < 16; d <<= 1) rs[r] += __shfl_xor(rs[r], d);
      l_r[r] = l_r[r] * al[r] + rs[r];
    }
#pragma unroll
    for (int ks2 = 0; ks2 < 2; ++ks2) {
      const s16x8 pa = *(const s16x8*)&PSf[(w * 16 + l16) * KST + ks2 * 32 + quad * 8];
#pragma unroll
      for (int c = 0; c < 4; ++c) {
        const s16x8 vb = *(const s16x8*)&VtS[(c * 16 + l16) * KST + ks2 * 32 + quad * 8];
        o_acc[c] = __builtin_amdgcn_mfma_f32_16x16x32_bf16(pa, vb, o_acc[c], 0, 0, 0);
      }
    }
  }
  float inv[4];
#pragma unroll
  for (int r = 0; r < 4; ++r) inv[r] = 1.0f / (l_r[r] * 0.9f);
#pragma unroll
  for (int c = 0; c < 4; ++c)
#pragma unroll
    for (int r = 0; r < 4; ++r)
      out[(bh * Sn + (size_t)(qbase + w * 16 + quad * 4 + r)) * Dn + c * 16 + l16] =
          o_acc[c][r] * inv[r];
}

extern "C" void kernel_launch(void* const* d_in, const int* in_sizes, int n_in,
                              void* d_out, int out_size, void* d_ws, size_t ws_size,
                              hipStream_t stream) {
  const float* Q = (const float*)d_in[0];
  const float* K = (const float*)d_in[1];
  const float* V = (const float*)d_in[2];
  const int* sf = (const int*)d_in[3];
  float* out = (float*)d_out;

  constexpr size_t ARR = (size_t)Bn * Hn * Sn * Dn;  // 4,194,304 elems (8 MB bf16)
  const size_t need = 3 * ARR * sizeof(uint16_t);    // 24 MB

  if (ws_size >= need) {
    uint16_t* Khg = (uint16_t*)d_ws;
    uint16_t* Klg = Khg + ARR;
    uint16_t* Vtg = Klg + ARR;
    prep_kv<<<dim3(16, 64), NT, 0, stream>>>(K, V, Khg, Klg, Vtg);
    attn_mfma7<<<dim3(Sn / TQM, Hn, Bn), NT, 0, stream>>>(Q, Khg, Klg, Vtg, V, sf, out);
  } else {
    attn_fallback<<<dim3(Sn / 64, Hn, Bn), NT, 0, stream>>>(Q, K, V, sf, out);
  }
}